// Round 16
// baseline (343.284 us; speedup 1.0000x reference)
//
#include <hip/hip_runtime.h>

#define NA 250000
#define NB 500000
#define NG 50000
#define DD 64
#define EA_N 1000000
#define EG_N 500000
#define FTC 320           // 5*64
#define NSEG (2 * NB)     // [0,NB) = a2b, [NB,2NB) = g2b
#define CAP 8             // bucket slots per (bond, etype)

#define EDGE4_BLKS (((EA_N + EG_N) / 4 + 255) / 256)   // 1465
#define COPYA_BLKS 1024
#define COPYG_BLKS 128
#define BOND_BLKS (NB / 16)     // 31250 (16 bonds/block, 16 lanes/bond)
#define REDO_BLKS 64

// workspace layout (ints)
#define WS_CNT       0            // 1,000,000 (NSEG)
#define WS_SPILL_CNT 1000000      // 1
#define WS_OVF_CNT   1000001      // 1 (pad to 1,000,016)
#define WS_OVF       1000016      // 1,000,000
#define WS_SPILL     2000016      // 1.5M int2 = 3,000,000 ints
#define WS_SLOTS     5000016      // NSEG*CAP = 8,000,000
#define WS_NEED_B    ((size_t)(5000016 + (size_t)NSEG * CAP) * 4)  // 52 MB

#define SPILL_MAX 1500000

// native clang vector type — required by __builtin_nontemporal_*
typedef float vf4 __attribute__((ext_vector_type(4)));

// ---------------- helpers ----------------

__device__ __forceinline__ float4 f4add(float4 a, float4 b) {
    return make_float4(a.x + b.x, a.y + b.y, a.z + b.z, a.w + b.w);
}
__device__ __forceinline__ float4 f4max(float4 a, float4 b) {
    return make_float4(fmaxf(a.x, b.x), fmaxf(a.y, b.y),
                       fmaxf(a.z, b.z), fmaxf(a.w, b.w));
}
__device__ __forceinline__ float4 f4scale(float4 a, float s) {
    return make_float4(a.x * s, a.y * s, a.z * s, a.w * s);
}
__device__ __forceinline__ float4 ntload4(const float4* p) {
    vf4 v = __builtin_nontemporal_load((const vf4*)p);
    return make_float4(v.x, v.y, v.z, v.w);
}
__device__ __forceinline__ void ntstore4(float4 a, float4* p) {
    vf4 v = {a.x, a.y, a.z, a.w};
    __builtin_nontemporal_store(v, (vf4*)p);
}
__device__ __forceinline__ int ntload_i(const int* p) {
    return __builtin_nontemporal_load(p);
}

// ---------------- phase 1: one-pass bucket build (edges only) ----------------

__global__ __launch_bounds__(256) void bucket_fill_kernel(
    const int4* __restrict__ a2b_src4, const int4* __restrict__ a2b_dst4,
    const int4* __restrict__ g2b_src4, const int4* __restrict__ g2b_dst4,
    int* __restrict__ cnt, int* __restrict__ slots,
    int2* __restrict__ spill, int* __restrict__ ovf,
    int* __restrict__ spill_cnt, int* __restrict__ ovf_cnt) {
    int i = blockIdx.x * blockDim.x + threadIdx.x;
    int stride = gridDim.x * blockDim.x;
    const int totalA = EA_N / 4;
    const int total = (EA_N + EG_N) / 4;
    for (; i < total; i += stride) {
        int4 d, s;
        int base;
        if (i < totalA) {
            d = a2b_dst4[i]; s = a2b_src4[i]; base = 0;
        } else {
            d = g2b_dst4[i - totalA]; s = g2b_src4[i - totalA]; base = NB;
        }
#define PUT(DX, SX)                                                         \
        {                                                                   \
            int seg = base + (DX);                                          \
            int pos = atomicAdd(&cnt[seg], 1);                              \
            if (pos < CAP) {                                                \
                slots[(size_t)seg * CAP + pos] = (SX);                      \
            } else {                                                        \
                int r = atomicAdd(spill_cnt, 1);                            \
                if (r < SPILL_MAX) spill[r] = make_int2(seg, (SX));         \
                if (pos == CAP) { int o = atomicAdd(ovf_cnt, 1); ovf[o] = seg; } \
            }                                                               \
        }
        PUT(d.x, s.x) PUT(d.y, s.y) PUT(d.z, s.z) PUT(d.w, s.w)
#undef PUT
    }
}

// ---------------- phase 2: bond rows + appended copies + appended redo ----------------
// blocks [0, BOND_BLKS): 16 bonds/block, 16 lanes (one float4 of the row) each.
//   Slot loads are predicated on degree (saves ~24 MB of read traffic) and
//   nontemporal (read-once ws data must not evict the atom table from L2).
// blocks [BOND_BLKS, +COPYA_BLKS): atom pass-through copy (proven tail placement).
// blocks [.., +COPYG_BLKS): global pass-through copy.
// blocks [.., +REDO_BLKS): exact redo for overflowed (deg > CAP) segments.

__global__ __launch_bounds__(256) void bond_copy_redo_kernel(
    const float4* __restrict__ bond4, const float4* __restrict__ atom4,
    const float4* __restrict__ glob4, const int* __restrict__ cnt,
    const int* __restrict__ slots, float4* __restrict__ ft4,
    float4* __restrict__ out_atom4, float4* __restrict__ out_glob4,
    const int2* __restrict__ spill, const int* __restrict__ spill_cnt,
    const int* __restrict__ ovf, const int* __restrict__ ovf_cnt,
    const float* __restrict__ atom, const float* __restrict__ glob,
    float* __restrict__ ft) {
    int bid = blockIdx.x;

    if (bid < BOND_BLKS) {
        long long b = (long long)bid * 16 + (threadIdx.x >> 4);
        int q = threadIdx.x & 15;
        int gbase = threadIdx.x & 48;

        // level 0: degrees + bond row
        int da = cnt[b];
        int dg = cnt[NB + b];
        float4 bv = ntload4(&bond4[b * 16 + q]);

        int na = min(da, CAP);
        int ng = min(dg, CAP);

        // level 1: predicated NT slot loads (only deg lanes issue)
        int ia = (q < na) ? ntload_i(&slots[(size_t)b * CAP + q]) : 0;
        int ig = (q < ng) ? ntload_i(&slots[(size_t)(NB + b) * CAP + q]) : 0;

        // level 2: gathers (independent within & across etypes)
        float4 sa = make_float4(0.f, 0.f, 0.f, 0.f), sg = sa;
        float4 xa = make_float4(-INFINITY, -INFINITY, -INFINITY, -INFINITY), xg = xa;

        for (int j = 0; j < na; ++j) {
            int s = __shfl(ia, gbase + j, 64);
            float4 v = atom4[(long long)s * 16 + q];
            sa = f4add(sa, v);
            xa = f4max(xa, v);
        }
        for (int j = 0; j < ng; ++j) {
            int s = __shfl(ig, gbase + j, 64);
            float4 v = glob4[(long long)s * 16 + q];
            sg = f4add(sg, v);
            xg = f4max(xg, v);
        }

        float4 ma = f4scale(sa, da ? 1.f / (float)da : 0.f);
        float4 mg = f4scale(sg, dg ? 1.f / (float)dg : 0.f);
        if (!da) xa = make_float4(0.f, 0.f, 0.f, 0.f);
        if (!dg) xg = make_float4(0.f, 0.f, 0.f, 0.f);

        float4* row = ft4 + b * 80;
        ntstore4(bv, &row[q]);
        if (da <= CAP) {                  // overflowed bonds: redo blocks write
            ntstore4(ma, &row[16 + q]);
            ntstore4(xa, &row[32 + q]);
        }
        if (dg <= CAP) {
            ntstore4(mg, &row[48 + q]);
            ntstore4(xg, &row[64 + q]);
        }
    } else if (bid < BOND_BLKS + COPYA_BLKS) {
        long long n4 = (long long)NA * DD / 4;
        long long i = (long long)(bid - BOND_BLKS) * 256 + threadIdx.x;
        long long stride = (long long)COPYA_BLKS * 256;
        for (; i < n4; i += stride) {
            float4 v = ntload4(&atom4[i]);
            ntstore4(v, &out_atom4[i]);
        }
    } else if (bid < BOND_BLKS + COPYA_BLKS + COPYG_BLKS) {
        long long n4 = (long long)NG * DD / 4;
        long long i = (long long)(bid - BOND_BLKS - COPYA_BLKS) * 256 + threadIdx.x;
        long long stride = (long long)COPYG_BLKS * 256;
        for (; i < n4; i += stride) {
            float4 v = ntload4(&glob4[i]);
            ntstore4(v, &out_glob4[i]);
        }
    } else {
        // redo role: one 64-lane wave per overflowed segment.
        int nov = *ovf_cnt;
        if (nov == 0) return;
        int nsp = min(*spill_cnt, SPILL_MAX);
        int rbid = bid - BOND_BLKS - COPYA_BLKS - COPYG_BLKS;
        int wid = (int)(((long long)rbid * 256 + threadIdx.x) >> 6);
        int lane = threadIdx.x & 63;
        const int nw = (REDO_BLKS * 256) >> 6;

        for (int o = wid; o < nov; o += nw) {
            int seg = ovf[o];
            int et = (seg >= NB) ? 1 : 0;
            const float* sft = et ? glob : atom;
            int deg = cnt[seg];

            float sum = 0.f, mx = -INFINITY;
            for (int j = 0; j < CAP; ++j) {
                int s = slots[(size_t)seg * CAP + j];
                float v = sft[(size_t)s * DD + lane];
                sum += v; mx = fmaxf(mx, v);
            }
            for (int base = 0; base < nsp; base += 64) {
                int e = base + lane;
                int sseg = -1, ssrc = 0;
                if (e < nsp) { int2 p = spill[e]; sseg = p.x; ssrc = p.y; }
                unsigned long long m = __ballot(sseg == seg);
                while (m) {
                    int l = __ffsll((unsigned long long)m) - 1;
                    m &= m - 1;
                    int s = __shfl(ssrc, l, 64);
                    float v = sft[(size_t)s * DD + lane];
                    sum += v; mx = fmaxf(mx, v);
                }
            }
            float mean = sum / (float)deg;    // deg > CAP > 0
            long long bb = et ? (seg - NB) : seg;
            float* row = ft + bb * (long long)FTC + (et ? 192 : 64);
            row[lane] = mean;
            row[64 + lane] = mx;
        }
    }
}

// ================= fallback path (small ws): direct atomic scatter =================

__device__ __forceinline__ unsigned float_to_key(float f) {
    unsigned u = __float_as_uint(f);
    return (u & 0x80000000u) ? ~u : (u | 0x80000000u);
}
__device__ __forceinline__ float key_to_float(unsigned k) {
    unsigned u = (k & 0x80000000u) ? (k & 0x7FFFFFFFu) : ~k;
    return __uint_as_float(u);
}

__global__ void fb_copy_kernel(const float4* __restrict__ src,
                               float4* __restrict__ dst, long long n4) {
    long long i = (long long)blockIdx.x * blockDim.x + threadIdx.x;
    long long stride = (long long)gridDim.x * blockDim.x;
    for (; i < n4; i += stride) dst[i] = src[i];
}

__global__ void fb_init_ft_kernel(const float4* __restrict__ bond,
                                  float4* __restrict__ ft) {
    const long long n4 = (long long)NB * 80;
    long long i = (long long)blockIdx.x * blockDim.x + threadIdx.x;
    long long stride = (long long)gridDim.x * blockDim.x;
    for (; i < n4; i += stride) {
        long long b = i / 80;
        int c4 = (int)(i - b * 80);
        float4 v = make_float4(0.f, 0.f, 0.f, 0.f);
        if (c4 < 16) v = bond[b * 16 + c4];
        ft[i] = v;
    }
}

__global__ void fb_scatter_kernel(const float* __restrict__ src_ft,
                                  const int* __restrict__ src_idx,
                                  const int* __restrict__ dst_idx,
                                  int n_edges, float* __restrict__ ft,
                                  int sum_col, int max_col,
                                  int* __restrict__ cnt) {
    long long total = (long long)n_edges * 64;
    long long i = (long long)blockIdx.x * blockDim.x + threadIdx.x;
    long long stride = (long long)gridDim.x * blockDim.x;
    for (; i < total; i += stride) {
        int e = (int)(i >> 6);
        int d = (int)(i & 63);
        int s = src_idx[e];
        int b = dst_idx[e];
        float v = src_ft[(long long)s * DD + d];
        atomicAdd(&ft[(long long)b * FTC + sum_col + d], v);
        atomicMax((unsigned*)&ft[(long long)b * FTC + max_col + d], float_to_key(v));
        if (d == 0) atomicAdd(&cnt[b], 1);
    }
}

__global__ void fb_finalize_kernel(float* __restrict__ ft,
                                   const int* __restrict__ cnt_a,
                                   const int* __restrict__ cnt_g) {
    long long total = (long long)NB * 64;
    long long i = (long long)blockIdx.x * blockDim.x + threadIdx.x;
    long long stride = (long long)gridDim.x * blockDim.x;
    for (; i < total; i += stride) {
        long long b = i >> 6;
        int d = (int)(i & 63);
        float* row = ft + b * FTC;
        int ca = cnt_a[b];
        row[64 + d] = row[64 + d] / fmaxf((float)ca, 1.0f);
        unsigned ka = __float_as_uint(row[128 + d]);
        row[128 + d] = (ca > 0) ? key_to_float(ka) : 0.0f;
        int cg = cnt_g[b];
        row[192 + d] = row[192 + d] / fmaxf((float)cg, 1.0f);
        unsigned kg = __float_as_uint(row[256 + d]);
        row[256 + d] = (cg > 0) ? key_to_float(kg) : 0.0f;
    }
}

// ---------------- launch ----------------

extern "C" void kernel_launch(void* const* d_in, const int* in_sizes, int n_in,
                              void* d_out, int out_size, void* d_ws, size_t ws_size,
                              hipStream_t stream) {
    const float* atom_ft   = (const float*)d_in[0];
    const float* bond_ft   = (const float*)d_in[1];
    const float* global_ft = (const float*)d_in[2];
    const int* a2b_src = (const int*)d_in[3];
    const int* a2b_dst = (const int*)d_in[4];
    const int* g2b_src = (const int*)d_in[5];
    const int* g2b_dst = (const int*)d_in[6];

    float* out = (float*)d_out;
    float* out_atom = out;                            // [NA,64]
    float* out_ft   = out + (long long)NA * DD;       // [NB,320]
    float* out_glob = out_ft + (long long)NB * FTC;   // [NG,64]

    int* ws = (int*)d_ws;
    const int BLK = 256;

    if (ws_size >= WS_NEED_B) {
        int* cnt       = ws + WS_CNT;
        int* spill_cnt = ws + WS_SPILL_CNT;
        int* ovf_cnt   = ws + WS_OVF_CNT;
        int* ovf       = ws + WS_OVF;
        int2* spill    = (int2*)(ws + WS_SPILL);
        int* slots     = ws + WS_SLOTS;

        // zero cnt + both counters in one memset
        (void)hipMemsetAsync(cnt, 0, (size_t)(WS_OVF) * 4, stream);

        bucket_fill_kernel<<<EDGE4_BLKS, BLK, 0, stream>>>(
            (const int4*)a2b_src, (const int4*)a2b_dst,
            (const int4*)g2b_src, (const int4*)g2b_dst,
            cnt, slots, spill, ovf, spill_cnt, ovf_cnt);

        bond_copy_redo_kernel<<<BOND_BLKS + COPYA_BLKS + COPYG_BLKS + REDO_BLKS,
                                BLK, 0, stream>>>(
            (const float4*)bond_ft, (const float4*)atom_ft,
            (const float4*)global_ft, cnt, slots, (float4*)out_ft,
            (float4*)out_atom, (float4*)out_glob,
            spill, spill_cnt, ovf, ovf_cnt, atom_ft, global_ft, out_ft);
    } else {
        // compact known-correct fallback (direct atomic scatter)
        int* cnt_a = ws;
        int* cnt_g = ws + NB;
        (void)hipMemsetAsync(ws, 0, 2 * (size_t)NB * sizeof(int), stream);
        fb_copy_kernel<<<4096, BLK, 0, stream>>>(
            (const float4*)atom_ft, (float4*)out_atom, (long long)NA * DD / 4);
        fb_copy_kernel<<<2048, BLK, 0, stream>>>(
            (const float4*)global_ft, (float4*)out_glob, (long long)NG * DD / 4);
        fb_init_ft_kernel<<<8192, BLK, 0, stream>>>(
            (const float4*)bond_ft, (float4*)out_ft);
        fb_scatter_kernel<<<8192, BLK, 0, stream>>>(
            atom_ft, a2b_src, a2b_dst, EA_N, out_ft, 64, 128, cnt_a);
        fb_scatter_kernel<<<8192, BLK, 0, stream>>>(
            global_ft, g2b_src, g2b_dst, EG_N, out_ft, 192, 256, cnt_g);
        fb_finalize_kernel<<<8192, BLK, 0, stream>>>(out_ft, cnt_a, cnt_g);
    }
}

// Round 17
// 328.289 us; speedup vs baseline: 1.0457x; 1.0457x over previous
//
#include <hip/hip_runtime.h>

#define NA 250000
#define NB 500000
#define NG 50000
#define DD 64
#define EA_N 1000000
#define EG_N 500000
#define FTC 320           // 5*64
#define NSEG (2 * NB)     // [0,NB) = a2b, [NB,2NB) = g2b
#define CAP 8             // bucket slots per (bond, etype)

#define EDGE4_BLKS (((EA_N + EG_N) / 4 + 255) / 256)   // 1465
#define COPYA_BLKS 1024
#define COPYG_BLKS 128
#define BOND_BLKS (NB / 16)     // 31250 (16 bonds/block, 16 lanes/bond)
#define REDO_BLKS 64

// workspace layout (ints)
#define WS_CNT       0            // 1,000,000 (NSEG)
#define WS_SPILL_CNT 1000000      // 1
#define WS_OVF_CNT   1000001      // 1 (pad to 1,000,016)
#define WS_OVF       1000016      // 1,000,000
#define WS_SPILL     2000016      // 1.5M int2 = 3,000,000 ints
#define WS_SLOTS     5000016      // NSEG*CAP = 8,000,000
#define WS_NEED_B    ((size_t)(5000016 + (size_t)NSEG * CAP) * 4)  // 52 MB

#define SPILL_MAX 1500000

// native clang vector type — required by __builtin_nontemporal_*
typedef float vf4 __attribute__((ext_vector_type(4)));

// ---------------- helpers ----------------

__device__ __forceinline__ float4 f4add(float4 a, float4 b) {
    return make_float4(a.x + b.x, a.y + b.y, a.z + b.z, a.w + b.w);
}
__device__ __forceinline__ float4 f4max(float4 a, float4 b) {
    return make_float4(fmaxf(a.x, b.x), fmaxf(a.y, b.y),
                       fmaxf(a.z, b.z), fmaxf(a.w, b.w));
}
__device__ __forceinline__ float4 f4scale(float4 a, float s) {
    return make_float4(a.x * s, a.y * s, a.z * s, a.w * s);
}
__device__ __forceinline__ float4 ntload4(const float4* p) {
    vf4 v = __builtin_nontemporal_load((const vf4*)p);
    return make_float4(v.x, v.y, v.z, v.w);
}
__device__ __forceinline__ void ntstore4(float4 a, float4* p) {
    vf4 v = {a.x, a.y, a.z, a.w};
    __builtin_nontemporal_store(v, (vf4*)p);
}

// ---------------- phase 1: one-pass bucket build (edges only) ----------------

__global__ __launch_bounds__(256) void bucket_fill_kernel(
    const int4* __restrict__ a2b_src4, const int4* __restrict__ a2b_dst4,
    const int4* __restrict__ g2b_src4, const int4* __restrict__ g2b_dst4,
    int* __restrict__ cnt, int* __restrict__ slots,
    int2* __restrict__ spill, int* __restrict__ ovf,
    int* __restrict__ spill_cnt, int* __restrict__ ovf_cnt) {
    int i = blockIdx.x * blockDim.x + threadIdx.x;
    int stride = gridDim.x * blockDim.x;
    const int totalA = EA_N / 4;
    const int total = (EA_N + EG_N) / 4;
    for (; i < total; i += stride) {
        int4 d, s;
        int base;
        if (i < totalA) {
            d = a2b_dst4[i]; s = a2b_src4[i]; base = 0;
        } else {
            d = g2b_dst4[i - totalA]; s = g2b_src4[i - totalA]; base = NB;
        }
#define PUT(DX, SX)                                                         \
        {                                                                   \
            int seg = base + (DX);                                          \
            int pos = atomicAdd(&cnt[seg], 1);                              \
            if (pos < CAP) {                                                \
                slots[(size_t)seg * CAP + pos] = (SX);                      \
            } else {                                                        \
                int r = atomicAdd(spill_cnt, 1);                            \
                if (r < SPILL_MAX) spill[r] = make_int2(seg, (SX));         \
                if (pos == CAP) { int o = atomicAdd(ovf_cnt, 1); ovf[o] = seg; } \
            }                                                               \
        }
        PUT(d.x, s.x) PUT(d.y, s.y) PUT(d.z, s.z) PUT(d.w, s.w)
#undef PUT
    }
}

// ---------------- phase 2: bond rows + appended copies + appended redo ----------------
// blocks [0, BOND_BLKS): 16 bonds/block, 16 lanes (one float4 of the row) each.
//   Level 0 fully parallel (static addresses): cnt, all slots, bond row issue
//   together — unpredicated (R16 showed predication serializes level-0).
// blocks [BOND_BLKS, +COPYA_BLKS): atom pass-through copy (proven tail placement).
// blocks [.., +COPYG_BLKS): global pass-through copy.
// blocks [.., +REDO_BLKS): exact redo for overflowed (deg > CAP) segments.

__global__ __launch_bounds__(256) void bond_copy_redo_kernel(
    const float4* __restrict__ bond4, const float4* __restrict__ atom4,
    const float4* __restrict__ glob4, const int* __restrict__ cnt,
    const int* __restrict__ slots, float4* __restrict__ ft4,
    float4* __restrict__ out_atom4, float4* __restrict__ out_glob4,
    const int2* __restrict__ spill, const int* __restrict__ spill_cnt,
    const int* __restrict__ ovf, const int* __restrict__ ovf_cnt,
    const float* __restrict__ atom, const float* __restrict__ glob,
    float* __restrict__ ft) {
    int bid = blockIdx.x;

    if (bid < BOND_BLKS) {
        long long b = (long long)bid * 16 + (threadIdx.x >> 4);
        int q = threadIdx.x & 15;
        int gbase = threadIdx.x & 48;

        // level 0: everything independent issues together
        int da = cnt[b];
        int dg = cnt[NB + b];
        int ia = (q < CAP) ? slots[(size_t)b * CAP + q] : 0;
        int ig = (q < CAP) ? slots[(size_t)(NB + b) * CAP + q] : 0;
        float4 bv = ntload4(&bond4[b * 16 + q]);

        int na = min(da, CAP);
        int ng = min(dg, CAP);

        // level 1: gathers (independent within & across etypes)
        float4 sa = make_float4(0.f, 0.f, 0.f, 0.f), sg = sa;
        float4 xa = make_float4(-INFINITY, -INFINITY, -INFINITY, -INFINITY), xg = xa;

        for (int j = 0; j < na; ++j) {
            int s = __shfl(ia, gbase + j, 64);
            float4 v = atom4[(long long)s * 16 + q];
            sa = f4add(sa, v);
            xa = f4max(xa, v);
        }
        for (int j = 0; j < ng; ++j) {
            int s = __shfl(ig, gbase + j, 64);
            float4 v = glob4[(long long)s * 16 + q];
            sg = f4add(sg, v);
            xg = f4max(xg, v);
        }

        float4 ma = f4scale(sa, da ? 1.f / (float)da : 0.f);
        float4 mg = f4scale(sg, dg ? 1.f / (float)dg : 0.f);
        if (!da) xa = make_float4(0.f, 0.f, 0.f, 0.f);
        if (!dg) xg = make_float4(0.f, 0.f, 0.f, 0.f);

        float4* row = ft4 + b * 80;
        ntstore4(bv, &row[q]);
        if (da <= CAP) {                  // overflowed bonds: redo blocks write
            ntstore4(ma, &row[16 + q]);
            ntstore4(xa, &row[32 + q]);
        }
        if (dg <= CAP) {
            ntstore4(mg, &row[48 + q]);
            ntstore4(xg, &row[64 + q]);
        }
    } else if (bid < BOND_BLKS + COPYA_BLKS) {
        long long n4 = (long long)NA * DD / 4;
        long long i = (long long)(bid - BOND_BLKS) * 256 + threadIdx.x;
        long long stride = (long long)COPYA_BLKS * 256;
        for (; i < n4; i += stride) {
            float4 v = ntload4(&atom4[i]);
            ntstore4(v, &out_atom4[i]);
        }
    } else if (bid < BOND_BLKS + COPYA_BLKS + COPYG_BLKS) {
        long long n4 = (long long)NG * DD / 4;
        long long i = (long long)(bid - BOND_BLKS - COPYA_BLKS) * 256 + threadIdx.x;
        long long stride = (long long)COPYG_BLKS * 256;
        for (; i < n4; i += stride) {
            float4 v = ntload4(&glob4[i]);
            ntstore4(v, &out_glob4[i]);
        }
    } else {
        // redo role: one 64-lane wave per overflowed segment.
        int nov = *ovf_cnt;
        if (nov == 0) return;
        int nsp = min(*spill_cnt, SPILL_MAX);
        int rbid = bid - BOND_BLKS - COPYA_BLKS - COPYG_BLKS;
        int wid = (int)(((long long)rbid * 256 + threadIdx.x) >> 6);
        int lane = threadIdx.x & 63;
        const int nw = (REDO_BLKS * 256) >> 6;

        for (int o = wid; o < nov; o += nw) {
            int seg = ovf[o];
            int et = (seg >= NB) ? 1 : 0;
            const float* sft = et ? glob : atom;
            int deg = cnt[seg];

            float sum = 0.f, mx = -INFINITY;
            for (int j = 0; j < CAP; ++j) {
                int s = slots[(size_t)seg * CAP + j];
                float v = sft[(size_t)s * DD + lane];
                sum += v; mx = fmaxf(mx, v);
            }
            for (int base = 0; base < nsp; base += 64) {
                int e = base + lane;
                int sseg = -1, ssrc = 0;
                if (e < nsp) { int2 p = spill[e]; sseg = p.x; ssrc = p.y; }
                unsigned long long m = __ballot(sseg == seg);
                while (m) {
                    int l = __ffsll((unsigned long long)m) - 1;
                    m &= m - 1;
                    int s = __shfl(ssrc, l, 64);
                    float v = sft[(size_t)s * DD + lane];
                    sum += v; mx = fmaxf(mx, v);
                }
            }
            float mean = sum / (float)deg;    // deg > CAP > 0
            long long bb = et ? (seg - NB) : seg;
            float* row = ft + bb * (long long)FTC + (et ? 192 : 64);
            row[lane] = mean;
            row[64 + lane] = mx;
        }
    }
}

// ================= fallback path (small ws): direct atomic scatter =================

__device__ __forceinline__ unsigned float_to_key(float f) {
    unsigned u = __float_as_uint(f);
    return (u & 0x80000000u) ? ~u : (u | 0x80000000u);
}
__device__ __forceinline__ float key_to_float(unsigned k) {
    unsigned u = (k & 0x80000000u) ? (k & 0x7FFFFFFFu) : ~k;
    return __uint_as_float(u);
}

__global__ void fb_copy_kernel(const float4* __restrict__ src,
                               float4* __restrict__ dst, long long n4) {
    long long i = (long long)blockIdx.x * blockDim.x + threadIdx.x;
    long long stride = (long long)gridDim.x * blockDim.x;
    for (; i < n4; i += stride) dst[i] = src[i];
}

__global__ void fb_init_ft_kernel(const float4* __restrict__ bond,
                                  float4* __restrict__ ft) {
    const long long n4 = (long long)NB * 80;
    long long i = (long long)blockIdx.x * blockDim.x + threadIdx.x;
    long long stride = (long long)gridDim.x * blockDim.x;
    for (; i < n4; i += stride) {
        long long b = i / 80;
        int c4 = (int)(i - b * 80);
        float4 v = make_float4(0.f, 0.f, 0.f, 0.f);
        if (c4 < 16) v = bond[b * 16 + c4];
        ft[i] = v;
    }
}

__global__ void fb_scatter_kernel(const float* __restrict__ src_ft,
                                  const int* __restrict__ src_idx,
                                  const int* __restrict__ dst_idx,
                                  int n_edges, float* __restrict__ ft,
                                  int sum_col, int max_col,
                                  int* __restrict__ cnt) {
    long long total = (long long)n_edges * 64;
    long long i = (long long)blockIdx.x * blockDim.x + threadIdx.x;
    long long stride = (long long)gridDim.x * blockDim.x;
    for (; i < total; i += stride) {
        int e = (int)(i >> 6);
        int d = (int)(i & 63);
        int s = src_idx[e];
        int b = dst_idx[e];
        float v = src_ft[(long long)s * DD + d];
        atomicAdd(&ft[(long long)b * FTC + sum_col + d], v);
        atomicMax((unsigned*)&ft[(long long)b * FTC + max_col + d], float_to_key(v));
        if (d == 0) atomicAdd(&cnt[b], 1);
    }
}

__global__ void fb_finalize_kernel(float* __restrict__ ft,
                                   const int* __restrict__ cnt_a,
                                   const int* __restrict__ cnt_g) {
    long long total = (long long)NB * 64;
    long long i = (long long)blockIdx.x * blockDim.x + threadIdx.x;
    long long stride = (long long)gridDim.x * blockDim.x;
    for (; i < total; i += stride) {
        long long b = i >> 6;
        int d = (int)(i & 63);
        float* row = ft + b * FTC;
        int ca = cnt_a[b];
        row[64 + d] = row[64 + d] / fmaxf((float)ca, 1.0f);
        unsigned ka = __float_as_uint(row[128 + d]);
        row[128 + d] = (ca > 0) ? key_to_float(ka) : 0.0f;
        int cg = cnt_g[b];
        row[192 + d] = row[192 + d] / fmaxf((float)cg, 1.0f);
        unsigned kg = __float_as_uint(row[256 + d]);
        row[256 + d] = (cg > 0) ? key_to_float(kg) : 0.0f;
    }
}

// ---------------- launch ----------------

extern "C" void kernel_launch(void* const* d_in, const int* in_sizes, int n_in,
                              void* d_out, int out_size, void* d_ws, size_t ws_size,
                              hipStream_t stream) {
    const float* atom_ft   = (const float*)d_in[0];
    const float* bond_ft   = (const float*)d_in[1];
    const float* global_ft = (const float*)d_in[2];
    const int* a2b_src = (const int*)d_in[3];
    const int* a2b_dst = (const int*)d_in[4];
    const int* g2b_src = (const int*)d_in[5];
    const int* g2b_dst = (const int*)d_in[6];

    float* out = (float*)d_out;
    float* out_atom = out;                            // [NA,64]
    float* out_ft   = out + (long long)NA * DD;       // [NB,320]
    float* out_glob = out_ft + (long long)NB * FTC;   // [NG,64]

    int* ws = (int*)d_ws;
    const int BLK = 256;

    if (ws_size >= WS_NEED_B) {
        int* cnt       = ws + WS_CNT;
        int* spill_cnt = ws + WS_SPILL_CNT;
        int* ovf_cnt   = ws + WS_OVF_CNT;
        int* ovf       = ws + WS_OVF;
        int2* spill    = (int2*)(ws + WS_SPILL);
        int* slots     = ws + WS_SLOTS;

        // zero cnt + both counters in one memset
        (void)hipMemsetAsync(cnt, 0, (size_t)(WS_OVF) * 4, stream);

        bucket_fill_kernel<<<EDGE4_BLKS, BLK, 0, stream>>>(
            (const int4*)a2b_src, (const int4*)a2b_dst,
            (const int4*)g2b_src, (const int4*)g2b_dst,
            cnt, slots, spill, ovf, spill_cnt, ovf_cnt);

        bond_copy_redo_kernel<<<BOND_BLKS + COPYA_BLKS + COPYG_BLKS + REDO_BLKS,
                                BLK, 0, stream>>>(
            (const float4*)bond_ft, (const float4*)atom_ft,
            (const float4*)global_ft, cnt, slots, (float4*)out_ft,
            (float4*)out_atom, (float4*)out_glob,
            spill, spill_cnt, ovf, ovf_cnt, atom_ft, global_ft, out_ft);
    } else {
        // compact known-correct fallback (direct atomic scatter)
        int* cnt_a = ws;
        int* cnt_g = ws + NB;
        (void)hipMemsetAsync(ws, 0, 2 * (size_t)NB * sizeof(int), stream);
        fb_copy_kernel<<<4096, BLK, 0, stream>>>(
            (const float4*)atom_ft, (float4*)out_atom, (long long)NA * DD / 4);
        fb_copy_kernel<<<2048, BLK, 0, stream>>>(
            (const float4*)global_ft, (float4*)out_glob, (long long)NG * DD / 4);
        fb_init_ft_kernel<<<8192, BLK, 0, stream>>>(
            (const float4*)bond_ft, (float4*)out_ft);
        fb_scatter_kernel<<<8192, BLK, 0, stream>>>(
            atom_ft, a2b_src, a2b_dst, EA_N, out_ft, 64, 128, cnt_a);
        fb_scatter_kernel<<<8192, BLK, 0, stream>>>(
            global_ft, g2b_src, g2b_dst, EG_N, out_ft, 192, 256, cnt_g);
        fb_finalize_kernel<<<8192, BLK, 0, stream>>>(out_ft, cnt_a, cnt_g);
    }
}